// Round 10
// baseline (3768.999 us; speedup 1.0000x reference)
//
#include <hip/hip_runtime.h>
#include <cstdint>

#define NTH 256

namespace {

constexpr int IMG_W   = 100;
constexpr int NS      = 64;
constexpr int D_PTS   = 63;
constexpr int D_DIR   = 27;
constexpr int HID     = 256;
constexpr int HID_DIR = 128;
constexpr int ENC_S   = 65;

__device__ __forceinline__ float4 ld4(const float* __restrict__ p, int idx, bool al) {
    if (al) {
        return *reinterpret_cast<const float4*>(p + idx);
    } else {
        float4 r; r.x = p[idx]; r.y = p[idx + 1]; r.z = p[idx + 2]; r.w = p[idx + 3];
        return r;
    }
}

__global__ __launch_bounds__(NTH, 2)
void nerf_fused(const float* __restrict__ c2w,
                const float* __restrict__ t_rand,
                const float* __restrict__ w1,  const float* __restrict__ b1,
                const float* __restrict__ w2,  const float* __restrict__ b2,
                const float* __restrict__ w_sig, const float* __restrict__ b_sig,
                const float* __restrict__ w_dir, const float* __restrict__ b_dir,
                const float* __restrict__ w_rgb, const float* __restrict__ b_rgb,
                float* __restrict__ out)
{
    __shared__ float encS[NS * ENC_S];   // 16640 B
    __shared__ float zbuf[NS];
    __shared__ float encdir[32];
    __shared__ float sigb[NS];
    __shared__ float rgbb[NS * 3];

    const int tid = threadIdx.x;
    const int ray = blockIdx.x;

    // ---- per-ray setup (uniform) ----
    const int pj = ray / IMG_W;
    const int pi = ray - pj * IMG_W;
    const float dx = ((float)pi - 50.0f) / 86.6f;
    const float dy = -(((float)pj) - 50.0f) / 86.6f;
    const float rd0 = dx * c2w[0] + dy * c2w[1] - c2w[2];
    const float rd1 = dx * c2w[4] + dy * c2w[5] - c2w[6];
    const float rd2 = dx * c2w[8] + dy * c2w[9] - c2w[10];
    const float ro0 = c2w[3], ro1 = c2w[7], ro2 = c2w[11];
    const float nrm = sqrtf(rd0 * rd0 + rd1 * rd1 + rd2 * rd2);
    const float vd0 = rd0 / nrm, vd1 = rd1 / nrm, vd2 = rd2 / nrm;

    // ---- z values: np.linspace-style f64 chain, rounded to f32 (t[63]=1 exact) ----
    if (tid < NS) {
        const int s = tid;
        const double delta = 1.0 / 63.0;
        const double ts = (s == 63) ? 1.0 : (double)s * delta;
        const double zs = 2.0 * (1.0 - ts) + 6.0 * ts;
        double lower, upper;
        if (s == 0) { lower = zs; }
        else { const double tm = (double)(s - 1) * delta;
               const double zm = 2.0 * (1.0 - tm) + 6.0 * tm; lower = 0.5 * (zm + zs); }
        if (s == 63) { upper = zs; }
        else { const double tp = (s + 1 == 63) ? 1.0 : (double)(s + 1) * delta;
               const double zp = 2.0 * (1.0 - tp) + 6.0 * tp; upper = 0.5 * (zs + zp); }
        zbuf[s] = (float)(lower + (upper - lower) * (double)t_rand[s]);
    }
    // ---- enc_dir (27 per-ray values) ----
    if (tid < D_DIR) {
        const int f = tid;
        float v;
        if (f < 3) {
            v = (f == 0) ? vd0 : ((f == 1) ? vd1 : vd2);
        } else {
            const int ff = f - 3;
            const int l = ff / 6;
            const int r = ff - 6 * l;
            const int c = r % 3;
            const float x = ((c == 0) ? vd0 : ((c == 1) ? vd1 : vd2)) * (float)(1 << l);
            v = (r < 3) ? sinf(x) : cosf(x);
        }
        encdir[f] = v;
    }
    __syncthreads();

    // ---- enc_pts [64][63] in LDS (fp32) ----
    for (int idx = tid; idx < NS * D_PTS; idx += NTH) {
        const int s = idx / D_PTS;
        const int f = idx - s * D_PTS;
        const float zv = zbuf[s];
        float v;
        if (f < 3) {
            v = (f == 0) ? (ro0 + rd0 * zv) : ((f == 1) ? (ro1 + rd1 * zv) : (ro2 + rd2 * zv));
        } else {
            const int ff = f - 3;
            const int l = ff / 6;
            const int r = ff - 6 * l;
            const int c = r % 3;
            const float p = (c == 0) ? (ro0 + rd0 * zv) : ((c == 1) ? (ro1 + rd1 * zv) : (ro2 + rd2 * zv));
            const float x = p * (float)(1 << l);
            v = (r < 3) ? sinf(x) : cosf(x);
        }
        encS[s * ENC_S + f] = v;
    }
    __syncthreads();

    // Thread (sg, jt): samples s0..s0+3, 16-neuron slice. h kept in registers,
    // shared across jt-lanes (same wave) via __shfl — full fp32 precision.
    const int sg = tid >> 4;
    const int jt = tid & 15;
    const int s0 = sg << 2;
    const int laneBase = tid & 48;

    const bool al = (((reinterpret_cast<uintptr_t>(w1) |
                       reinterpret_cast<uintptr_t>(w2) |
                       reinterpret_cast<uintptr_t>(w_dir)) & 15) == 0);

    // ---------------- layer 1: h1 = relu(enc @ w1 + b1) ----------------
    float h1r[4][16];
    {
        const int j0 = jt << 4;
        float acc[4][16];
        #pragma unroll
        for (int i = 0; i < 4; ++i)
            #pragma unroll
            for (int j = 0; j < 16; ++j) acc[i][j] = 0.0f;

        for (int k = 0; k < D_PTS; ++k) {
            float wv[16];
            float4 q0 = ld4(w1, k * HID + j0,      al);
            float4 q1 = ld4(w1, k * HID + j0 + 4,  al);
            float4 q2 = ld4(w1, k * HID + j0 + 8,  al);
            float4 q3 = ld4(w1, k * HID + j0 + 12, al);
            wv[0]=q0.x; wv[1]=q0.y; wv[2]=q0.z; wv[3]=q0.w;
            wv[4]=q1.x; wv[5]=q1.y; wv[6]=q1.z; wv[7]=q1.w;
            wv[8]=q2.x; wv[9]=q2.y; wv[10]=q2.z; wv[11]=q2.w;
            wv[12]=q3.x; wv[13]=q3.y; wv[14]=q3.z; wv[15]=q3.w;
            float ev[4];
            #pragma unroll
            for (int i = 0; i < 4; ++i) ev[i] = encS[(s0 + i) * ENC_S + k];
            #pragma unroll
            for (int i = 0; i < 4; ++i)
                #pragma unroll
                for (int j = 0; j < 16; ++j) acc[i][j] += ev[i] * wv[j];
        }
        #pragma unroll
        for (int i = 0; i < 4; ++i)
            #pragma unroll
            for (int j = 0; j < 16; ++j)
                h1r[i][j] = fmaxf(acc[i][j] + b1[j0 + j], 0.0f);
    }

    // ---------------- layer 2: h2 = relu(h1 @ w2 + b2) ----------------
    float h2r[4][16];
    {
        const int j0 = jt << 4;
        float acc[4][16];
        #pragma unroll
        for (int i = 0; i < 4; ++i)
            #pragma unroll
            for (int j = 0; j < 16; ++j) acc[i][j] = 0.0f;

        for (int kj = 0; kj < 16; ++kj) {
            const int src = laneBase + kj;
            #pragma unroll
            for (int kr = 0; kr < 16; ++kr) {
                const int k = kj * 16 + kr;
                float wv[16];
                float4 q0 = ld4(w2, k * HID + j0,      al);
                float4 q1 = ld4(w2, k * HID + j0 + 4,  al);
                float4 q2 = ld4(w2, k * HID + j0 + 8,  al);
                float4 q3 = ld4(w2, k * HID + j0 + 12, al);
                wv[0]=q0.x; wv[1]=q0.y; wv[2]=q0.z; wv[3]=q0.w;
                wv[4]=q1.x; wv[5]=q1.y; wv[6]=q1.z; wv[7]=q1.w;
                wv[8]=q2.x; wv[9]=q2.y; wv[10]=q2.z; wv[11]=q2.w;
                wv[12]=q3.x; wv[13]=q3.y; wv[14]=q3.z; wv[15]=q3.w;
                float ev[4];
                #pragma unroll
                for (int i = 0; i < 4; ++i) ev[i] = __shfl(h1r[i][kr], src, 64);
                #pragma unroll
                for (int i = 0; i < 4; ++i)
                    #pragma unroll
                    for (int j = 0; j < 16; ++j) acc[i][j] += ev[i] * wv[j];
            }
        }
        #pragma unroll
        for (int i = 0; i < 4; ++i)
            #pragma unroll
            for (int j = 0; j < 16; ++j)
                h2r[i][j] = fmaxf(acc[i][j] + b2[j0 + j], 0.0f);
    }

    // ---------------- sigma: plain fp32 dot + wave reduce ----------------
    {
        const int j0 = jt << 4;
        float p[4];
        #pragma unroll
        for (int i = 0; i < 4; ++i) p[i] = 0.0f;
        #pragma unroll
        for (int j = 0; j < 16; ++j) {
            const float ws = w_sig[j0 + j];
            #pragma unroll
            for (int i = 0; i < 4; ++i) p[i] += h2r[i][j] * ws;
        }
        #pragma unroll
        for (int off = 1; off < 16; off <<= 1) {
            #pragma unroll
            for (int i = 0; i < 4; ++i) p[i] += __shfl_xor(p[i], off, 64);
        }
        if (jt == 0) {
            #pragma unroll
            for (int i = 0; i < 4; ++i) sigb[s0 + i] = p[i] + b_sig[0];
        }
    }

    // ---------------- dir layer: hd = relu([h2, enc_dir] @ w_dir + b_dir) --
    float hdr[4][8];
    {
        const int j0d = jt << 3;
        float accd[4][8];
        #pragma unroll
        for (int i = 0; i < 4; ++i)
            #pragma unroll
            for (int j = 0; j < 8; ++j) accd[i][j] = 0.0f;

        for (int kj = 0; kj < 16; ++kj) {
            const int src = laneBase + kj;
            #pragma unroll
            for (int kr = 0; kr < 16; ++kr) {
                const int k = kj * 16 + kr;
                float wv[8];
                float4 q0 = ld4(w_dir, k * HID_DIR + j0d,     al);
                float4 q1 = ld4(w_dir, k * HID_DIR + j0d + 4, al);
                wv[0]=q0.x; wv[1]=q0.y; wv[2]=q0.z; wv[3]=q0.w;
                wv[4]=q1.x; wv[5]=q1.y; wv[6]=q1.z; wv[7]=q1.w;
                float ev[4];
                #pragma unroll
                for (int i = 0; i < 4; ++i) ev[i] = __shfl(h2r[i][kr], src, 64);
                #pragma unroll
                for (int i = 0; i < 4; ++i)
                    #pragma unroll
                    for (int j = 0; j < 8; ++j) accd[i][j] += ev[i] * wv[j];
            }
        }
        // enc_dir tail — identical for all samples of this ray
        float db[8];
        #pragma unroll
        for (int j = 0; j < 8; ++j) db[j] = 0.0f;
        for (int t = 0; t < D_DIR; ++t) {
            const float ed = encdir[t];
            #pragma unroll
            for (int j = 0; j < 8; ++j) db[j] += ed * w_dir[(HID + t) * HID_DIR + j0d + j];
        }
        #pragma unroll
        for (int i = 0; i < 4; ++i)
            #pragma unroll
            for (int j = 0; j < 8; ++j)
                hdr[i][j] = fmaxf(accd[i][j] + db[j] + b_dir[j0d + j], 0.0f);
    }

    // ---------------- rgb head: sigmoid(hd @ w_rgb + b_rgb) ---------------
    {
        const int j0d = jt << 3;
        float pr[4][3];
        #pragma unroll
        for (int i = 0; i < 4; ++i)
            #pragma unroll
            for (int c = 0; c < 3; ++c) pr[i][c] = 0.0f;
        #pragma unroll
        for (int j = 0; j < 8; ++j) {
            const float wr0 = w_rgb[(j0d + j) * 3 + 0];
            const float wr1 = w_rgb[(j0d + j) * 3 + 1];
            const float wr2 = w_rgb[(j0d + j) * 3 + 2];
            #pragma unroll
            for (int i = 0; i < 4; ++i) {
                pr[i][0] += hdr[i][j] * wr0;
                pr[i][1] += hdr[i][j] * wr1;
                pr[i][2] += hdr[i][j] * wr2;
            }
        }
        #pragma unroll
        for (int off = 1; off < 16; off <<= 1) {
            #pragma unroll
            for (int i = 0; i < 4; ++i)
                #pragma unroll
                for (int c = 0; c < 3; ++c)
                    pr[i][c] += __shfl_xor(pr[i][c], off, 64);
        }
        if (jt == 0) {
            #pragma unroll
            for (int i = 0; i < 4; ++i)
                #pragma unroll
                for (int c = 0; c < 3; ++c) {
                    const float a = pr[i][c] + b_rgb[c];
                    rgbb[(s0 + i) * 3 + c] = 1.0f / (1.0f + expf(-a));
                }
        }
    }
    __syncthreads();

    // ---------------- volume compositing (wave 0) -------------------------
    if (tid < NS) {
        const int s = tid;
        const float sgv = sigb[s];
        const float zv  = zbuf[s];
        const float zn  = (s < 63) ? zbuf[s + 1] : 0.0f;
        const float dist = (s < 63) ? (zn - zv) : 1.0e10f;
        const float alpha = 1.0f - expf(-fmaxf(sgv, 0.0f) * dist * nrm);
        float P = 1.0f - alpha;
        #pragma unroll
        for (int off = 1; off < 64; off <<= 1) {
            const float p = __shfl_up(P, off, 64);
            if (s >= off) P *= p;
        }
        float T = __shfl_up(P, 1, 64);
        if (s == 0) T = 1.0f;
        const float wgt = alpha * T;
        float r0 = wgt * rgbb[s * 3 + 0];
        float r1 = wgt * rgbb[s * 3 + 1];
        float r2 = wgt * rgbb[s * 3 + 2];
        #pragma unroll
        for (int off = 32; off > 0; off >>= 1) {
            r0 += __shfl_xor(r0, off, 64);
            r1 += __shfl_xor(r1, off, 64);
            r2 += __shfl_xor(r2, off, 64);
        }
        if (s == 0) {
            // d_out is FLOAT32 (= reference output dtype, per harness rule)
            out[ray * 3 + 0] = r0;
            out[ray * 3 + 1] = r1;
            out[ray * 3 + 2] = r2;
        }
    }
}

} // namespace

extern "C" void kernel_launch(void* const* d_in, const int* in_sizes, int n_in,
                              void* d_out, int out_size, void* d_ws, size_t ws_size,
                              hipStream_t stream) {
    const float* c2w    = (const float*)d_in[0];
    const float* t_rand = (const float*)d_in[1];
    const float* w1     = (const float*)d_in[2];
    const float* b1     = (const float*)d_in[3];
    const float* w2     = (const float*)d_in[4];
    const float* b2     = (const float*)d_in[5];
    const float* w_sig  = (const float*)d_in[6];
    const float* b_sig  = (const float*)d_in[7];
    const float* w_dir  = (const float*)d_in[8];
    const float* b_dir  = (const float*)d_in[9];
    const float* w_rgb  = (const float*)d_in[10];
    const float* b_rgb  = (const float*)d_in[11];

    (void)in_sizes; (void)n_in; (void)d_ws; (void)ws_size; (void)out_size;

    hipLaunchKernelGGL(nerf_fused, dim3(100 * 100), dim3(NTH), 0, stream,
                       c2w, t_rand, w1, b1, w2, b2, w_sig, b_sig,
                       w_dir, b_dir, w_rgb, b_rgb, (float*)d_out);
}

// Round 11
// 3725.674 us; speedup vs baseline: 1.0116x; 1.0116x over previous
//
#include <hip/hip_runtime.h>
#include <hip/hip_fp16.h>
#include <cstdint>
#include <cmath>

#define NTH 256

namespace {

constexpr int IMG_W   = 100;
constexpr int NS      = 64;
constexpr int D_PTS   = 63;
constexpr int D_DIR   = 27;
constexpr int HID     = 256;
constexpr int HID_DIR = 128;
constexpr int ENC_S   = 65;    // enc row stride (floats): conflict-free
constexpr int H_S     = 258;   // h stride (halfs): sg-group bank step 4 -> 2-way (free)
constexpr int HD_S    = 130;   // hd stride (halfs)

__device__ __forceinline__ float4 ld4(const float* __restrict__ p, int idx, bool al) {
    if (al) {
        return *reinterpret_cast<const float4*>(p + idx);
    } else {
        float4 r; r.x = p[idx]; r.y = p[idx + 1]; r.z = p[idx + 2]; r.w = p[idx + 3];
        return r;
    }
}

// Slim-register structure: activations live in fp16 LDS (no shuffle sharing, no
// big register arrays -> ~90-110 VGPRs in the hot loops) so launch_bounds(256,4)
// holds 4 waves/SIMD without AGPR parking (R10: 108 VGPR + ~100 AGPR -> 2 waves).
// fp16 sigma noise (~1e-3) would flip the terminal-sample razor
// alpha[63]=1-exp(-relu(sig63)*1e10*nrm)  (R1 failed exactly so at 0.4997);
// the f64 razor below recomputes sigma[63] end-to-end in float64 (matches the
// np reference's float64-promoted z chain to ~1e-13).
__global__ __launch_bounds__(NTH, 4)
void nerf_fused(const float* __restrict__ c2w,
                const float* __restrict__ t_rand,
                const float* __restrict__ w1,  const float* __restrict__ b1,
                const float* __restrict__ w2,  const float* __restrict__ b2,
                const float* __restrict__ w_sig, const float* __restrict__ b_sig,
                const float* __restrict__ w_dir, const float* __restrict__ b_dir,
                const float* __restrict__ w_rgb, const float* __restrict__ b_rgb,
                float* __restrict__ out)
{
    // scrA: encS (layer-1 phase, 16640 B) aliased by the razor's f64 buffers
    // (razor runs after encS is dead). Total LDS = 52.6 KB -> 3 blocks/CU.
    __shared__ __align__(16) unsigned char scrA[16640];
    float*  encS = reinterpret_cast<float*>(scrA);
    double* encD = reinterpret_cast<double*>(scrA);           //  512 B
    double* h1d  = reinterpret_cast<double*>(scrA + 512);     // 2048 B
    double* h2d  = reinterpret_cast<double*>(scrA + 2560);    // 2048 B
    __shared__ __align__(16) __half hbuf[NS * H_S];           // 33024 B (h1->h2->hd)
    __shared__ float  zbuf[NS];
    __shared__ double zd[NS];
    __shared__ float  encdir[32];
    __shared__ float  sigp[NTH];
    __shared__ float  sigb[NS];
    __shared__ float  rgbb[NS * 3];

    const int tid = threadIdx.x;
    const int ray = blockIdx.x;

    // ---- per-ray setup (uniform; plain fp32 as in the passing R10) ----
    const int pj = ray / IMG_W;
    const int pi = ray - pj * IMG_W;
    const float dx = ((float)pi - 50.0f) / 86.6f;
    const float dy = -(((float)pj) - 50.0f) / 86.6f;
    const float rd0 = dx * c2w[0] + dy * c2w[1] - c2w[2];
    const float rd1 = dx * c2w[4] + dy * c2w[5] - c2w[6];
    const float rd2 = dx * c2w[8] + dy * c2w[9] - c2w[10];
    const float ro0 = c2w[3], ro1 = c2w[7], ro2 = c2w[11];
    const float nrm = sqrtf(rd0 * rd0 + rd1 * rd1 + rd2 * rd2);
    const float vd0 = rd0 / nrm, vd1 = rd1 / nrm, vd2 = rd2 / nrm;

    // ---- z: np.linspace-style f64 chain (t[63]=1 exact) ----
    if (tid < NS) {
        const int s = tid;
        const double delta = 1.0 / 63.0;
        const double ts = (s == 63) ? 1.0 : (double)s * delta;
        const double zs = 2.0 * (1.0 - ts) + 6.0 * ts;
        double lower, upper;
        if (s == 0) { lower = zs; }
        else { const double tm = (double)(s - 1) * delta;
               const double zm = 2.0 * (1.0 - tm) + 6.0 * tm; lower = 0.5 * (zm + zs); }
        if (s == 63) { upper = zs; }
        else { const double tp = (s + 1 == 63) ? 1.0 : (double)(s + 1) * delta;
               const double zp = 2.0 * (1.0 - tp) + 6.0 * tp; upper = 0.5 * (zs + zp); }
        const double zz = lower + (upper - lower) * (double)t_rand[s];
        zd[s]   = zz;
        zbuf[s] = (float)zz;
    }
    if (tid < D_DIR) {
        const int f = tid;
        float v;
        if (f < 3) {
            v = (f == 0) ? vd0 : ((f == 1) ? vd1 : vd2);
        } else {
            const int ff = f - 3;
            const int l = ff / 6;
            const int r = ff - 6 * l;
            const int c = r % 3;
            const float x = ((c == 0) ? vd0 : ((c == 1) ? vd1 : vd2)) * (float)(1 << l);
            v = (r < 3) ? sinf(x) : cosf(x);
        }
        encdir[f] = v;
    }
    __syncthreads();

    // ---- enc_pts [64][63] fp32 in LDS ----
    for (int idx = tid; idx < NS * D_PTS; idx += NTH) {
        const int s = idx / D_PTS;
        const int f = idx - s * D_PTS;
        const float zv = zbuf[s];
        float v;
        if (f < 3) {
            v = (f == 0) ? (ro0 + rd0 * zv) : ((f == 1) ? (ro1 + rd1 * zv) : (ro2 + rd2 * zv));
        } else {
            const int ff = f - 3;
            const int l = ff / 6;
            const int r = ff - 6 * l;
            const int c = r % 3;
            const float p = (c == 0) ? (ro0 + rd0 * zv) : ((c == 1) ? (ro1 + rd1 * zv) : (ro2 + rd2 * zv));
            const float x = p * (float)(1 << l);
            v = (r < 3) ? sinf(x) : cosf(x);
        }
        encS[s * ENC_S + f] = v;
    }
    __syncthreads();

    const int sg = tid >> 4;   // sample group: samples 4*sg..4*sg+3
    const int jt = tid & 15;   // neuron slice
    const int s0 = sg << 2;

    const bool al = (((reinterpret_cast<uintptr_t>(w1) |
                       reinterpret_cast<uintptr_t>(w2) |
                       reinterpret_cast<uintptr_t>(w_dir)) & 15) == 0);

    // ---------------- layer 1: h1 = relu(enc @ w1 + b1) -> fp16 LDS ----------
    {
        const int j0 = jt << 4;
        float acc[4][16];
        #pragma unroll
        for (int i = 0; i < 4; ++i)
            #pragma unroll
            for (int j = 0; j < 16; ++j) acc[i][j] = 0.0f;
        for (int k = 0; k < D_PTS; ++k) {
            float wv[16];
            float4 q0 = ld4(w1, k * HID + j0,      al);
            float4 q1 = ld4(w1, k * HID + j0 + 4,  al);
            float4 q2 = ld4(w1, k * HID + j0 + 8,  al);
            float4 q3 = ld4(w1, k * HID + j0 + 12, al);
            wv[0]=q0.x; wv[1]=q0.y; wv[2]=q0.z; wv[3]=q0.w;
            wv[4]=q1.x; wv[5]=q1.y; wv[6]=q1.z; wv[7]=q1.w;
            wv[8]=q2.x; wv[9]=q2.y; wv[10]=q2.z; wv[11]=q2.w;
            wv[12]=q3.x; wv[13]=q3.y; wv[14]=q3.z; wv[15]=q3.w;
            float ev[4];
            #pragma unroll
            for (int i = 0; i < 4; ++i) ev[i] = encS[(s0 + i) * ENC_S + k];
            #pragma unroll
            for (int i = 0; i < 4; ++i)
                #pragma unroll
                for (int j = 0; j < 16; ++j) acc[i][j] += ev[i] * wv[j];
        }
        #pragma unroll
        for (int i = 0; i < 4; ++i) {
            #pragma unroll
            for (int m = 0; m < 8; ++m) {
                const float a0 = fmaxf(acc[i][2*m]   + b1[j0 + 2*m],   0.0f);
                const float a1 = fmaxf(acc[i][2*m+1] + b1[j0 + 2*m+1], 0.0f);
                *reinterpret_cast<__half2*>(&hbuf[(s0 + i) * H_S + j0 + 2*m]) =
                    __floats2half2_rn(a0, a1);
            }
        }
    }
    __syncthreads();

    // ---------------- layer 2: h2 = relu(h1 @ w2 + b2) ----------------------
    {
        const int j0 = jt << 4;
        float acc[4][16];
        #pragma unroll
        for (int i = 0; i < 4; ++i)
            #pragma unroll
            for (int j = 0; j < 16; ++j) acc[i][j] = 0.0f;
        for (int k = 0; k < HID; ++k) {
            float wv[16];
            float4 q0 = ld4(w2, k * HID + j0,      al);
            float4 q1 = ld4(w2, k * HID + j0 + 4,  al);
            float4 q2 = ld4(w2, k * HID + j0 + 8,  al);
            float4 q3 = ld4(w2, k * HID + j0 + 12, al);
            wv[0]=q0.x; wv[1]=q0.y; wv[2]=q0.z; wv[3]=q0.w;
            wv[4]=q1.x; wv[5]=q1.y; wv[6]=q1.z; wv[7]=q1.w;
            wv[8]=q2.x; wv[9]=q2.y; wv[10]=q2.z; wv[11]=q2.w;
            wv[12]=q3.x; wv[13]=q3.y; wv[14]=q3.z; wv[15]=q3.w;
            float ev[4];
            #pragma unroll
            for (int i = 0; i < 4; ++i) ev[i] = __half2float(hbuf[(s0 + i) * H_S + k]);
            #pragma unroll
            for (int i = 0; i < 4; ++i)
                #pragma unroll
                for (int j = 0; j < 16; ++j) acc[i][j] += ev[i] * wv[j];
        }
        __syncthreads();   // all h1 reads complete before overwrite
        #pragma unroll
        for (int i = 0; i < 4; ++i) {
            #pragma unroll
            for (int m = 0; m < 8; ++m) {
                const float a0 = fmaxf(acc[i][2*m]   + b2[j0 + 2*m],   0.0f);
                const float a1 = fmaxf(acc[i][2*m+1] + b2[j0 + 2*m+1], 0.0f);
                *reinterpret_cast<__half2*>(&hbuf[(s0 + i) * H_S + j0 + 2*m]) =
                    __floats2half2_rn(a0, a1);
            }
        }
    }
    __syncthreads();

    // ---------------- sigma partials (fp32; s=63 re-done in f64 below) ------
    {
        const int s  = tid & 63;
        const int k0 = (tid >> 6) << 6;
        float a = 0.0f;
        for (int k = 0; k < 64; ++k)
            a += __half2float(hbuf[s * H_S + k0 + k]) * w_sig[k0 + k];
        sigp[tid] = a;
    }

    // ---------------- dir layer: hd = relu([h2, enc_dir] @ w_dir + b_dir) ---
    float hdr[4][8];
    {
        const int j0d = jt << 3;
        float accd[4][8];
        #pragma unroll
        for (int i = 0; i < 4; ++i)
            #pragma unroll
            for (int j = 0; j < 8; ++j) accd[i][j] = 0.0f;
        for (int k = 0; k < HID; ++k) {
            float wv[8];
            float4 q0 = ld4(w_dir, k * HID_DIR + j0d,     al);
            float4 q1 = ld4(w_dir, k * HID_DIR + j0d + 4, al);
            wv[0]=q0.x; wv[1]=q0.y; wv[2]=q0.z; wv[3]=q0.w;
            wv[4]=q1.x; wv[5]=q1.y; wv[6]=q1.z; wv[7]=q1.w;
            float ev[4];
            #pragma unroll
            for (int i = 0; i < 4; ++i) ev[i] = __half2float(hbuf[(s0 + i) * H_S + k]);
            #pragma unroll
            for (int i = 0; i < 4; ++i)
                #pragma unroll
                for (int j = 0; j < 8; ++j) accd[i][j] += ev[i] * wv[j];
        }
        float db[8];
        #pragma unroll
        for (int j = 0; j < 8; ++j) db[j] = 0.0f;
        for (int t = 0; t < D_DIR; ++t) {
            const float ed = encdir[t];
            #pragma unroll
            for (int j = 0; j < 8; ++j) db[j] += ed * w_dir[(HID + t) * HID_DIR + j0d + j];
        }
        #pragma unroll
        for (int i = 0; i < 4; ++i)
            #pragma unroll
            for (int j = 0; j < 8; ++j)
                hdr[i][j] = fmaxf(accd[i][j] + db[j] + b_dir[j0d + j], 0.0f);
    }
    __syncthreads();   // all h2 reads (sigma + dir) complete

    if (tid < NS) {
        sigb[tid] = sigp[tid] + sigp[tid + 64] + sigp[tid + 128] + sigp[tid + 192] + b_sig[0];
    }
    {
        const int j0d = jt << 3;
        #pragma unroll
        for (int i = 0; i < 4; ++i)
            #pragma unroll
            for (int m = 0; m < 4; ++m)
                *reinterpret_cast<__half2*>(&hbuf[(s0 + i) * HD_S + j0d + 2*m]) =
                    __floats2half2_rn(hdr[i][2*m], hdr[i][2*m+1]);
    }
    __syncthreads();

    // ---------------- rgb head: sigmoid(hd @ w_rgb + b_rgb) -----------------
    {
        const int s = tid & 63;
        const int c = tid >> 6;
        if (c < 3) {
            float a = 0.0f;
            for (int k = 0; k < HID_DIR; ++k)
                a += __half2float(hbuf[s * HD_S + k]) * w_rgb[k * 3 + c];
            a += b_rgb[c];
            rgbb[s * 3 + c] = 1.0f / (1.0f + expf(-a));
        }
    }
    __syncthreads();

    // ======== FLOAT64 razor: recompute sigma[63] (aliases dead encS) ========
    {
        const double z63 = zd[63];
        const double p0 = (double)ro0 + (double)rd0 * z63;
        const double p1 = (double)ro1 + (double)rd1 * z63;
        const double p2 = (double)ro2 + (double)rd2 * z63;
        if (tid < D_PTS) {
            const int f = tid;
            double v;
            if (f < 3) {
                v = (f == 0) ? p0 : ((f == 1) ? p1 : p2);
            } else {
                const int ff = f - 3;
                const int l = ff / 6;
                const int r = ff - 6 * l;
                const int c = r % 3;
                const double x = ((c == 0) ? p0 : ((c == 1) ? p1 : p2)) * (double)(1 << l);
                v = (r < 3) ? sin(x) : cos(x);
            }
            encD[f] = v;
        }
    }
    __syncthreads();
    {
        double acc = 0.0;
        for (int k = 0; k < D_PTS; ++k)
            acc += encD[k] * (double)w1[k * HID + tid];
        acc += (double)b1[tid];
        h1d[tid] = fmax(acc, 0.0);
    }
    __syncthreads();
    {
        double acc = 0.0;
        for (int k = 0; k < HID; ++k)
            acc += h1d[k] * (double)w2[k * HID + tid];
        acc += (double)b2[tid];
        h2d[tid] = fmax(acc, 0.0);
    }
    __syncthreads();
    if (tid < 64) {
        double p = 0.0;
        #pragma unroll
        for (int m = 0; m < 4; ++m)
            p += h2d[tid * 4 + m] * (double)w_sig[tid * 4 + m];
        #pragma unroll
        for (int off = 1; off < 64; off <<= 1)
            p += __shfl_xor(p, off, 64);
        if (tid == 0) sigb[63] = (float)(p + (double)b_sig[0]);
    }
    __syncthreads();

    // ---------------- volume compositing (wave 0) ---------------------------
    if (tid < NS) {
        const int s = tid;
        const float sgv = sigb[s];
        const float zv  = zbuf[s];
        const float zn  = (s < 63) ? zbuf[s + 1] : 0.0f;
        const float dist = (s < 63) ? (zn - zv) : 1.0e10f;
        const float alpha = 1.0f - expf(-fmaxf(sgv, 0.0f) * dist * nrm);
        float P = 1.0f - alpha;
        #pragma unroll
        for (int off = 1; off < 64; off <<= 1) {
            const float p = __shfl_up(P, off, 64);
            if (s >= off) P *= p;
        }
        float T = __shfl_up(P, 1, 64);
        if (s == 0) T = 1.0f;
        const float wgt = alpha * T;
        float r0 = wgt * rgbb[s * 3 + 0];
        float r1 = wgt * rgbb[s * 3 + 1];
        float r2 = wgt * rgbb[s * 3 + 2];
        #pragma unroll
        for (int off = 32; off > 0; off >>= 1) {
            r0 += __shfl_xor(r0, off, 64);
            r1 += __shfl_xor(r1, off, 64);
            r2 += __shfl_xor(r2, off, 64);
        }
        if (s == 0) {
            out[ray * 3 + 0] = r0;   // d_out is FLOAT32 (verified R10)
            out[ray * 3 + 1] = r1;
            out[ray * 3 + 2] = r2;
        }
    }
}

} // namespace

extern "C" void kernel_launch(void* const* d_in, const int* in_sizes, int n_in,
                              void* d_out, int out_size, void* d_ws, size_t ws_size,
                              hipStream_t stream) {
    const float* c2w    = (const float*)d_in[0];
    const float* t_rand = (const float*)d_in[1];
    const float* w1     = (const float*)d_in[2];
    const float* b1     = (const float*)d_in[3];
    const float* w2     = (const float*)d_in[4];
    const float* b2     = (const float*)d_in[5];
    const float* w_sig  = (const float*)d_in[6];
    const float* b_sig  = (const float*)d_in[7];
    const float* w_dir  = (const float*)d_in[8];
    const float* b_dir  = (const float*)d_in[9];
    const float* w_rgb  = (const float*)d_in[10];
    const float* b_rgb  = (const float*)d_in[11];

    (void)in_sizes; (void)n_in; (void)d_ws; (void)ws_size; (void)out_size;

    hipLaunchKernelGGL(nerf_fused, dim3(100 * 100), dim3(NTH), 0, stream,
                       c2w, t_rand, w1, b1, w2, b2, w_sig, b_sig,
                       w_dir, b_dir, w_rgb, b_rgb, (float*)d_out);
}

// Round 12
// 484.970 us; speedup vs baseline: 7.7716x; 7.6823x over previous
//
#include <hip/hip_runtime.h>
#include <cstdint>
#include <cmath>

#define NTH 256

namespace {

typedef _Float16 half8 __attribute__((ext_vector_type(8)));
typedef float    float4v __attribute__((ext_vector_type(4)));

constexpr int IMG_W   = 100;
constexpr int NS      = 64;
constexpr int D_PTS   = 63;
constexpr int D_DIR   = 27;
constexpr int HID     = 256;
constexpr int HID_DIR = 128;

constexpr int ENC_H = 72;    // enc stride (halfs): 144B rows, 16B-aligned k-runs
constexpr int H_S   = 264;   // hbuf stride (halfs): 528B rows, 16B-aligned
constexpr int HD_S  = 136;   // hd stride (halfs): 272B rows

// B fragment for mfma_f32_16x16x32_f16: lane supplies B[k=kbase+j][n], j=0..7.
// Row-major fp32 W[ldK x ldN]; 8 scalar loads (lanes 0-15 consecutive n -> coalesced).
__device__ __forceinline__ half8 bfrag(const float* __restrict__ W, int ldN,
                                       int kbase, int n, int kmax) {
    half8 b;
    #pragma unroll
    for (int j = 0; j < 8; ++j) {
        const int k = kbase + j;
        b[j] = (_Float16)((k < kmax) ? W[k * ldN + n] : 0.0f);
    }
    return b;
}

__global__ __launch_bounds__(NTH, 3)
void nerf_fused(const float* __restrict__ c2w,
                const float* __restrict__ t_rand,
                const float* __restrict__ w1,  const float* __restrict__ b1,
                const float* __restrict__ w2,  const float* __restrict__ b2,
                const float* __restrict__ w_sig, const float* __restrict__ b_sig,
                const float* __restrict__ w_dir, const float* __restrict__ b_dir,
                const float* __restrict__ w_rgb, const float* __restrict__ b_rgb,
                float* __restrict__ out)
{
    // scrA: encH (fp16 enc, layer-1 only) aliased later by the f64 razor buffers.
    __shared__ __align__(16) unsigned char scrA[NS * ENC_H * 2];       // 9216 B
    _Float16* encH = reinterpret_cast<_Float16*>(scrA);
    double*   encD = reinterpret_cast<double*>(scrA);                  //  512 B
    double*   h1d  = reinterpret_cast<double*>(scrA + 512);            // 2048 B
    double*   h2d  = reinterpret_cast<double*>(scrA + 2560);           // 2048 B
    __shared__ __align__(16) _Float16 hbuf[NS * H_S];                  // 33792 B (h1->h2->hd)
    __shared__ float  zbuf[NS];
    __shared__ double zd[NS];
    __shared__ float  encdir[32];
    __shared__ float  sigp[NTH];
    __shared__ float  sigb[NS];
    __shared__ float  rgbb[NS * 3];

    const int tid  = threadIdx.x;
    const int ray  = blockIdx.x;
    const int lane = tid & 63;
    const int wv   = tid >> 6;    // wave 0..3
    const int lr   = lane & 15;   // row/col within 16-tile
    const int lq   = lane >> 4;   // quad 0..3

    // ---- per-ray setup ----
    const int pj = ray / IMG_W;
    const int pi = ray - pj * IMG_W;
    const float dx = ((float)pi - 50.0f) / 86.6f;
    const float dy = -(((float)pj) - 50.0f) / 86.6f;
    const float rd0 = dx * c2w[0] + dy * c2w[1] - c2w[2];
    const float rd1 = dx * c2w[4] + dy * c2w[5] - c2w[6];
    const float rd2 = dx * c2w[8] + dy * c2w[9] - c2w[10];
    const float ro0 = c2w[3], ro1 = c2w[7], ro2 = c2w[11];
    const float nrm = sqrtf(rd0 * rd0 + rd1 * rd1 + rd2 * rd2);
    const float vd0 = rd0 / nrm, vd1 = rd1 / nrm, vd2 = rd2 / nrm;

    // ---- z: np.linspace-style f64 chain (t[63]=1 exact) ----
    if (tid < NS) {
        const int s = tid;
        const double delta = 1.0 / 63.0;
        const double ts = (s == 63) ? 1.0 : (double)s * delta;
        const double zs = 2.0 * (1.0 - ts) + 6.0 * ts;
        double lower, upper;
        if (s == 0) { lower = zs; }
        else { const double tm = (double)(s - 1) * delta;
               const double zm = 2.0 * (1.0 - tm) + 6.0 * tm; lower = 0.5 * (zm + zs); }
        if (s == 63) { upper = zs; }
        else { const double tp = (s + 1 == 63) ? 1.0 : (double)(s + 1) * delta;
               const double zp = 2.0 * (1.0 - tp) + 6.0 * tp; upper = 0.5 * (zs + zp); }
        const double zz = lower + (upper - lower) * (double)t_rand[s];
        zd[s]   = zz;
        zbuf[s] = (float)zz;
    }
    if (tid < D_DIR) {
        const int f = tid;
        float v;
        if (f < 3) {
            v = (f == 0) ? vd0 : ((f == 1) ? vd1 : vd2);
        } else {
            const int ff = f - 3;
            const int l = ff / 6;
            const int r = ff - 6 * l;
            const int c = r % 3;
            const float x = ((c == 0) ? vd0 : ((c == 1) ? vd1 : vd2)) * (float)(1 << l);
            v = (r < 3) ? sinf(x) : cosf(x);
        }
        encdir[f] = v;
    }
    __syncthreads();

    // ---- enc_pts [64][63] -> fp16 LDS (col 63 zero-padded for K=64) ----
    for (int idx = tid; idx < NS * 64; idx += NTH) {
        const int s = idx >> 6;
        const int f = idx & 63;
        float v = 0.0f;
        if (f < D_PTS) {
            const float zv = zbuf[s];
            if (f < 3) {
                v = (f == 0) ? (ro0 + rd0 * zv) : ((f == 1) ? (ro1 + rd1 * zv) : (ro2 + rd2 * zv));
            } else {
                const int ff = f - 3;
                const int l = ff / 6;
                const int r = ff - 6 * l;
                const int c = r % 3;
                const float p = (c == 0) ? (ro0 + rd0 * zv) : ((c == 1) ? (ro1 + rd1 * zv) : (ro2 + rd2 * zv));
                const float x = p * (float)(1 << l);
                v = (r < 3) ? sinf(x) : cosf(x);
            }
        }
        encH[s * ENC_H + f] = (_Float16)v;
    }
    __syncthreads();

    // ======== layer 1 (MFMA): H1 = relu(enc @ w1 + b1) ========
    // wave wv owns n-tiles {4wv..4wv+3} (64 neurons); all 4 m-tiles.
    {
        float4v acc[4][4];
        #pragma unroll
        for (int mt = 0; mt < 4; ++mt)
            #pragma unroll
            for (int nt = 0; nt < 4; ++nt) acc[mt][nt] = float4v{0.f, 0.f, 0.f, 0.f};

        #pragma unroll
        for (int ks = 0; ks < 2; ++ks) {
            half8 a[4];
            #pragma unroll
            for (int mt = 0; mt < 4; ++mt)
                a[mt] = *reinterpret_cast<const half8*>(&encH[(mt * 16 + lr) * ENC_H + ks * 32 + lq * 8]);
            #pragma unroll
            for (int nt = 0; nt < 4; ++nt) {
                const int n = (wv * 4 + nt) * 16 + lr;
                const half8 b = bfrag(w1, HID, ks * 32 + lq * 8, n, D_PTS);
                #pragma unroll
                for (int mt = 0; mt < 4; ++mt)
                    acc[mt][nt] = __builtin_amdgcn_mfma_f32_16x16x32_f16(a[mt], b, acc[mt][nt], 0, 0, 0);
            }
        }
        // epilogue: C layout row = mt*16 + lq*4 + r, col = n
        #pragma unroll
        for (int nt = 0; nt < 4; ++nt) {
            const int n = (wv * 4 + nt) * 16 + lr;
            const float bb = b1[n];
            #pragma unroll
            for (int mt = 0; mt < 4; ++mt)
                #pragma unroll
                for (int r = 0; r < 4; ++r)
                    hbuf[(mt * 16 + lq * 4 + r) * H_S + n] = (_Float16)fmaxf(acc[mt][nt][r] + bb, 0.0f);
        }
    }
    __syncthreads();

    // ======== layer 2 (MFMA): H2 = relu(H1 @ w2 + b2) ========
    {
        float4v acc[4][4];
        #pragma unroll
        for (int mt = 0; mt < 4; ++mt)
            #pragma unroll
            for (int nt = 0; nt < 4; ++nt) acc[mt][nt] = float4v{0.f, 0.f, 0.f, 0.f};

        for (int ks = 0; ks < 8; ++ks) {
            half8 a[4];
            #pragma unroll
            for (int mt = 0; mt < 4; ++mt)
                a[mt] = *reinterpret_cast<const half8*>(&hbuf[(mt * 16 + lr) * H_S + ks * 32 + lq * 8]);
            #pragma unroll
            for (int nt = 0; nt < 4; ++nt) {
                const int n = (wv * 4 + nt) * 16 + lr;
                const half8 b = bfrag(w2, HID, ks * 32 + lq * 8, n, 1 << 30);
                #pragma unroll
                for (int mt = 0; mt < 4; ++mt)
                    acc[mt][nt] = __builtin_amdgcn_mfma_f32_16x16x32_f16(a[mt], b, acc[mt][nt], 0, 0, 0);
            }
        }
        __syncthreads();   // all H1 reads complete before overwrite
        #pragma unroll
        for (int nt = 0; nt < 4; ++nt) {
            const int n = (wv * 4 + nt) * 16 + lr;
            const float bb = b2[n];
            #pragma unroll
            for (int mt = 0; mt < 4; ++mt)
                #pragma unroll
                for (int r = 0; r < 4; ++r)
                    hbuf[(mt * 16 + lq * 4 + r) * H_S + n] = (_Float16)fmaxf(acc[mt][nt][r] + bb, 0.0f);
        }
    }
    __syncthreads();

    // ======== sigma partials (fp32, vectorized LDS reads) ========
    {
        const int s  = tid & 63;
        const int k0 = (tid >> 6) << 6;
        float a = 0.0f;
        #pragma unroll
        for (int i = 0; i < 8; ++i) {
            const half8 h = *reinterpret_cast<const half8*>(&hbuf[s * H_S + k0 + i * 8]);
            #pragma unroll
            for (int j = 0; j < 8; ++j) a += (float)h[j] * w_sig[k0 + i * 8 + j];
        }
        sigp[tid] = a;
    }

    // ======== dir layer (MFMA): HD = relu([H2, enc_dir] @ w_dir + b_dir) ====
    float4v accd[4][2];
    float   db[2];
    {
        #pragma unroll
        for (int mt = 0; mt < 4; ++mt)
            #pragma unroll
            for (int nt = 0; nt < 2; ++nt) accd[mt][nt] = float4v{0.f, 0.f, 0.f, 0.f};

        for (int ks = 0; ks < 8; ++ks) {
            half8 a[4];
            #pragma unroll
            for (int mt = 0; mt < 4; ++mt)
                a[mt] = *reinterpret_cast<const half8*>(&hbuf[(mt * 16 + lr) * H_S + ks * 32 + lq * 8]);
            #pragma unroll
            for (int nt = 0; nt < 2; ++nt) {
                const int n = (wv * 2 + nt) * 16 + lr;
                const half8 b = bfrag(w_dir, HID_DIR, ks * 32 + lq * 8, n, 1 << 30);
                #pragma unroll
                for (int mt = 0; mt < 4; ++mt)
                    accd[mt][nt] = __builtin_amdgcn_mfma_f32_16x16x32_f16(a[mt], b, accd[mt][nt], 0, 0, 0);
            }
        }
        // enc_dir tail + bias (fp32, per lane-column)
        #pragma unroll
        for (int nt = 0; nt < 2; ++nt) {
            const int n = (wv * 2 + nt) * 16 + lr;
            float d = b_dir[n];
            for (int t = 0; t < D_DIR; ++t)
                d += encdir[t] * w_dir[(HID + t) * HID_DIR + n];
            db[nt] = d;
        }
    }
    __syncthreads();   // all H2 reads (sigma + dir) complete

    if (tid < NS) {
        sigb[tid] = sigp[tid] + sigp[tid + 64] + sigp[tid + 128] + sigp[tid + 192] + b_sig[0];
    }
    #pragma unroll
    for (int nt = 0; nt < 2; ++nt) {
        const int n = (wv * 2 + nt) * 16 + lr;
        #pragma unroll
        for (int mt = 0; mt < 4; ++mt)
            #pragma unroll
            for (int r = 0; r < 4; ++r)
                hbuf[(mt * 16 + lq * 4 + r) * HD_S + n] = (_Float16)fmaxf(accd[mt][nt][r] + db[nt], 0.0f);
    }
    __syncthreads();

    // ======== rgb head (fp32) ========
    {
        const int s = tid & 63;
        const int c = tid >> 6;
        if (c < 3) {
            float a = 0.0f;
            #pragma unroll
            for (int i = 0; i < 16; ++i) {
                const half8 h = *reinterpret_cast<const half8*>(&hbuf[s * HD_S + i * 8]);
                #pragma unroll
                for (int j = 0; j < 8; ++j) a += (float)h[j] * w_rgb[(i * 8 + j) * 3 + c];
            }
            a += b_rgb[c];
            rgbb[s * 3 + c] = 1.0f / (1.0f + expf(-a));
        }
    }
    __syncthreads();

    // ======== conditional f64 razor for sigma[63] ========
    // alpha[63] = 1-exp(-relu(sig63)*1e10*nrm) is a sign-step; fp16-path sigma
    // error <~3e-3, so only blocks with |sig63| < 0.02 need the exact recompute.
    // Block-uniform branch (sigb[63] identical across threads) -> barriers legal.
    if (fabsf(sigb[63]) < 0.02f) {
        {
            const double z63 = zd[63];
            const double p0 = (double)ro0 + (double)rd0 * z63;
            const double p1 = (double)ro1 + (double)rd1 * z63;
            const double p2 = (double)ro2 + (double)rd2 * z63;
            if (tid < D_PTS) {
                const int f = tid;
                double v;
                if (f < 3) {
                    v = (f == 0) ? p0 : ((f == 1) ? p1 : p2);
                } else {
                    const int ff = f - 3;
                    const int l = ff / 6;
                    const int r = ff - 6 * l;
                    const int c = r % 3;
                    const double x = ((c == 0) ? p0 : ((c == 1) ? p1 : p2)) * (double)(1 << l);
                    v = (r < 3) ? sin(x) : cos(x);
                }
                encD[f] = v;
            }
        }
        __syncthreads();
        {
            double acc = 0.0;
            for (int k = 0; k < D_PTS; ++k)
                acc += encD[k] * (double)w1[k * HID + tid];
            acc += (double)b1[tid];
            h1d[tid] = fmax(acc, 0.0);
        }
        __syncthreads();
        {
            double acc = 0.0;
            for (int k = 0; k < HID; ++k)
                acc += h1d[k] * (double)w2[k * HID + tid];
            acc += (double)b2[tid];
            h2d[tid] = fmax(acc, 0.0);
        }
        __syncthreads();
        if (tid < 64) {
            double p = 0.0;
            #pragma unroll
            for (int m = 0; m < 4; ++m)
                p += h2d[tid * 4 + m] * (double)w_sig[tid * 4 + m];
            #pragma unroll
            for (int off = 1; off < 64; off <<= 1)
                p += __shfl_xor(p, off, 64);
            if (tid == 0) sigb[63] = (float)(p + (double)b_sig[0]);
        }
    }
    __syncthreads();

    // ======== volume compositing (wave 0) ========
    if (tid < NS) {
        const int s = tid;
        const float sgv = sigb[s];
        const float zv  = zbuf[s];
        const float zn  = (s < 63) ? zbuf[s + 1] : 0.0f;
        const float dist = (s < 63) ? (zn - zv) : 1.0e10f;
        const float alpha = 1.0f - expf(-fmaxf(sgv, 0.0f) * dist * nrm);
        float P = 1.0f - alpha;
        #pragma unroll
        for (int off = 1; off < 64; off <<= 1) {
            const float p = __shfl_up(P, off, 64);
            if (s >= off) P *= p;
        }
        float T = __shfl_up(P, 1, 64);
        if (s == 0) T = 1.0f;
        const float wgt = alpha * T;
        float r0 = wgt * rgbb[s * 3 + 0];
        float r1 = wgt * rgbb[s * 3 + 1];
        float r2 = wgt * rgbb[s * 3 + 2];
        #pragma unroll
        for (int off = 32; off > 0; off >>= 1) {
            r0 += __shfl_xor(r0, off, 64);
            r1 += __shfl_xor(r1, off, 64);
            r2 += __shfl_xor(r2, off, 64);
        }
        if (s == 0) {
            out[ray * 3 + 0] = r0;   // d_out is FLOAT32 (verified R10)
            out[ray * 3 + 1] = r1;
            out[ray * 3 + 2] = r2;
        }
    }
}

} // namespace

extern "C" void kernel_launch(void* const* d_in, const int* in_sizes, int n_in,
                              void* d_out, int out_size, void* d_ws, size_t ws_size,
                              hipStream_t stream) {
    const float* c2w    = (const float*)d_in[0];
    const float* t_rand = (const float*)d_in[1];
    const float* w1     = (const float*)d_in[2];
    const float* b1     = (const float*)d_in[3];
    const float* w2     = (const float*)d_in[4];
    const float* b2     = (const float*)d_in[5];
    const float* w_sig  = (const float*)d_in[6];
    const float* b_sig  = (const float*)d_in[7];
    const float* w_dir  = (const float*)d_in[8];
    const float* b_dir  = (const float*)d_in[9];
    const float* w_rgb  = (const float*)d_in[10];
    const float* b_rgb  = (const float*)d_in[11];

    (void)in_sizes; (void)n_in; (void)d_ws; (void)ws_size; (void)out_size;

    hipLaunchKernelGGL(nerf_fused, dim3(100 * 100), dim3(NTH), 0, stream,
                       c2w, t_rand, w1, b1, w2, b2, w_sig, b_sig,
                       w_dir, b_dir, w_rgb, b_rgb, (float*)d_out);
}

// Round 13
// 380.654 us; speedup vs baseline: 9.9014x; 1.2740x over previous
//
#include <hip/hip_runtime.h>
#include <cstdint>
#include <cmath>

#define NTH 256

namespace {

typedef _Float16 half8 __attribute__((ext_vector_type(8)));
typedef float    float4v __attribute__((ext_vector_type(4)));

constexpr int IMG_W   = 100;
constexpr int NS      = 64;
constexpr int D_PTS   = 63;
constexpr int D_DIR   = 27;
constexpr int HID     = 256;
constexpr int HID_DIR = 128;

constexpr int ENC_H = 72;    // enc stride (halfs)
constexpr int H_S   = 264;   // hbuf stride (halfs)
constexpr int HD_S  = 136;   // hd stride (halfs)

// Packed-weight geometry (halfs): frag = 64 lanes x 8 halfs, laid out so one
// dwordx4 per lane fetches a whole B fragment, coalesced across the wave.
//   w1p: [ks=2][ntile=16][lane=64][8]  = 16384 halfs @ offset 0
//   w2p: [ks=8][ntile=16][lane=64][8]  = 65536 halfs @ offset 16384
//   wdp: [ks=8][ntile= 8][lane=64][8]  = 32768 halfs @ offset 81920
constexpr int W1P_OFF = 0;
constexpr int W2P_OFF = 16384;
constexpr int WDP_OFF = 81920;
constexpr int WPACK_HALFS = 114688;           // 229376 bytes

__global__ __launch_bounds__(NTH)
void prepack(const float* __restrict__ w1, const float* __restrict__ w2,
             const float* __restrict__ wd, _Float16* __restrict__ wp)
{
    const int idx = blockIdx.x * NTH + threadIdx.x;
    if (idx < W2P_OFF) {                       // w1 frags (K pad 63->64)
        const int j = idx & 7, lane = (idx >> 3) & 63, nt = (idx >> 9) & 15, ks = idx >> 13;
        const int k = ks * 32 + (lane >> 4) * 8 + j;
        const int n = nt * 16 + (lane & 15);
        wp[idx] = (_Float16)((k < D_PTS) ? w1[k * HID + n] : 0.0f);
    } else if (idx < WDP_OFF) {                // w2 frags
        const int t = idx - W2P_OFF;
        const int j = t & 7, lane = (t >> 3) & 63, nt = (t >> 9) & 15, ks = t >> 13;
        const int k = ks * 32 + (lane >> 4) * 8 + j;
        const int n = nt * 16 + (lane & 15);
        wp[idx] = (_Float16)w2[k * HID + n];
    } else if (idx < WPACK_HALFS) {            // w_dir frags (first 256 k-rows)
        const int t = idx - WDP_OFF;
        const int j = t & 7, lane = (t >> 3) & 63, nt = (t >> 9) & 7, ks = t >> 12;
        const int k = ks * 32 + (lane >> 4) * 8 + j;
        const int n = nt * 16 + (lane & 15);
        wp[idx] = (_Float16)wd[k * HID_DIR + n];
    }
}

// Fallback B-fragment gather (verified in R12): 8 scalar fp32 loads + cvt.
__device__ __forceinline__ half8 bfrag(const float* __restrict__ W, int ldN,
                                       int kbase, int n, int kmax) {
    half8 b;
    #pragma unroll
    for (int j = 0; j < 8; ++j) {
        const int k = kbase + j;
        b[j] = (_Float16)((k < kmax) ? W[k * ldN + n] : 0.0f);
    }
    return b;
}

template<bool PACKED>
__global__ __launch_bounds__(NTH, 3)
void nerf_fused(const float* __restrict__ c2w,
                const float* __restrict__ t_rand,
                const float* __restrict__ w1,  const float* __restrict__ b1,
                const float* __restrict__ w2,  const float* __restrict__ b2,
                const float* __restrict__ w_sig, const float* __restrict__ b_sig,
                const float* __restrict__ w_dir, const float* __restrict__ b_dir,
                const float* __restrict__ w_rgb, const float* __restrict__ b_rgb,
                const _Float16* __restrict__ wpack,
                float* __restrict__ out)
{
    __shared__ __align__(16) unsigned char scrA[NS * ENC_H * 2];       // 9216 B
    _Float16* encH = reinterpret_cast<_Float16*>(scrA);
    double*   encD = reinterpret_cast<double*>(scrA);                  //  512 B
    double*   h1d  = reinterpret_cast<double*>(scrA + 512);            // 2048 B
    double*   h2d  = reinterpret_cast<double*>(scrA + 2560);           // 2048 B
    __shared__ __align__(16) _Float16 hbuf[NS * H_S];                  // 33792 B
    __shared__ float  zbuf[NS];
    __shared__ double zd[NS];
    __shared__ float  encdir[32];
    __shared__ float  sigp[NTH];
    __shared__ float  sigb[NS];
    __shared__ float  rgbb[NS * 3];

    const int tid  = threadIdx.x;
    const int ray  = blockIdx.x;
    const int lane = tid & 63;
    const int wv   = tid >> 6;
    const int lr   = lane & 15;
    const int lq   = lane >> 4;

    const half8* wp8 = reinterpret_cast<const half8*>(wpack);

    // ---- per-ray setup ----
    const int pj = ray / IMG_W;
    const int pi = ray - pj * IMG_W;
    const float dx = ((float)pi - 50.0f) / 86.6f;
    const float dy = -(((float)pj) - 50.0f) / 86.6f;
    const float rd0 = dx * c2w[0] + dy * c2w[1] - c2w[2];
    const float rd1 = dx * c2w[4] + dy * c2w[5] - c2w[6];
    const float rd2 = dx * c2w[8] + dy * c2w[9] - c2w[10];
    const float ro0 = c2w[3], ro1 = c2w[7], ro2 = c2w[11];
    const float nrm = sqrtf(rd0 * rd0 + rd1 * rd1 + rd2 * rd2);
    const float vd0 = rd0 / nrm, vd1 = rd1 / nrm, vd2 = rd2 / nrm;

    // ---- z: np.linspace-style f64 chain (t[63]=1 exact) ----
    if (tid < NS) {
        const int s = tid;
        const double delta = 1.0 / 63.0;
        const double ts = (s == 63) ? 1.0 : (double)s * delta;
        const double zs = 2.0 * (1.0 - ts) + 6.0 * ts;
        double lower, upper;
        if (s == 0) { lower = zs; }
        else { const double tm = (double)(s - 1) * delta;
               const double zm = 2.0 * (1.0 - tm) + 6.0 * tm; lower = 0.5 * (zm + zs); }
        if (s == 63) { upper = zs; }
        else { const double tp = (s + 1 == 63) ? 1.0 : (double)(s + 1) * delta;
               const double zp = 2.0 * (1.0 - tp) + 6.0 * tp; upper = 0.5 * (zs + zp); }
        const double zz = lower + (upper - lower) * (double)t_rand[s];
        zd[s]   = zz;
        zbuf[s] = (float)zz;
    }
    if (tid < D_DIR) {
        const int f = tid;
        float v;
        if (f < 3) {
            v = (f == 0) ? vd0 : ((f == 1) ? vd1 : vd2);
        } else {
            const int ff = f - 3;
            const int l = ff / 6;
            const int r = ff - 6 * l;
            const int c = r % 3;
            const float x = ((c == 0) ? vd0 : ((c == 1) ? vd1 : vd2)) * (float)(1 << l);
            v = (r < 3) ? sinf(x) : cosf(x);
        }
        encdir[f] = v;
    }
    __syncthreads();

    // ---- enc_pts [64][63] -> fp16 LDS (col 63 zero-padded) ----
    for (int idx = tid; idx < NS * 64; idx += NTH) {
        const int s = idx >> 6;
        const int f = idx & 63;
        float v = 0.0f;
        if (f < D_PTS) {
            const float zv = zbuf[s];
            if (f < 3) {
                v = (f == 0) ? (ro0 + rd0 * zv) : ((f == 1) ? (ro1 + rd1 * zv) : (ro2 + rd2 * zv));
            } else {
                const int ff = f - 3;
                const int l = ff / 6;
                const int r = ff - 6 * l;
                const int c = r % 3;
                const float p = (c == 0) ? (ro0 + rd0 * zv) : ((c == 1) ? (ro1 + rd1 * zv) : (ro2 + rd2 * zv));
                const float x = p * (float)(1 << l);
                v = (r < 3) ? sinf(x) : cosf(x);
            }
        }
        encH[s * ENC_H + f] = (_Float16)v;
    }
    __syncthreads();

    // ======== layer 1 (MFMA): H1 = relu(enc @ w1 + b1) ========
    {
        float4v acc[4][4];
        #pragma unroll
        for (int mt = 0; mt < 4; ++mt)
            #pragma unroll
            for (int nt = 0; nt < 4; ++nt) acc[mt][nt] = float4v{0.f, 0.f, 0.f, 0.f};

        #pragma unroll
        for (int ks = 0; ks < 2; ++ks) {
            half8 a[4];
            #pragma unroll
            for (int mt = 0; mt < 4; ++mt)
                a[mt] = *reinterpret_cast<const half8*>(&encH[(mt * 16 + lr) * ENC_H + ks * 32 + lq * 8]);
            #pragma unroll
            for (int nt = 0; nt < 4; ++nt) {
                const int tile = wv * 4 + nt;
                const half8 b = PACKED
                    ? wp8[(W1P_OFF >> 3) + (ks * 16 + tile) * 64 + lane]
                    : bfrag(w1, HID, ks * 32 + lq * 8, tile * 16 + lr, D_PTS);
                #pragma unroll
                for (int mt = 0; mt < 4; ++mt)
                    acc[mt][nt] = __builtin_amdgcn_mfma_f32_16x16x32_f16(a[mt], b, acc[mt][nt], 0, 0, 0);
            }
        }
        #pragma unroll
        for (int nt = 0; nt < 4; ++nt) {
            const int n = (wv * 4 + nt) * 16 + lr;
            const float bb = b1[n];
            #pragma unroll
            for (int mt = 0; mt < 4; ++mt)
                #pragma unroll
                for (int r = 0; r < 4; ++r)
                    hbuf[(mt * 16 + lq * 4 + r) * H_S + n] = (_Float16)fmaxf(acc[mt][nt][r] + bb, 0.0f);
        }
    }
    __syncthreads();

    // ======== layer 2 (MFMA): H2 = relu(H1 @ w2 + b2) ========
    {
        float4v acc[4][4];
        #pragma unroll
        for (int mt = 0; mt < 4; ++mt)
            #pragma unroll
            for (int nt = 0; nt < 4; ++nt) acc[mt][nt] = float4v{0.f, 0.f, 0.f, 0.f};

        for (int ks = 0; ks < 8; ++ks) {
            half8 a[4];
            #pragma unroll
            for (int mt = 0; mt < 4; ++mt)
                a[mt] = *reinterpret_cast<const half8*>(&hbuf[(mt * 16 + lr) * H_S + ks * 32 + lq * 8]);
            #pragma unroll
            for (int nt = 0; nt < 4; ++nt) {
                const int tile = wv * 4 + nt;
                const half8 b = PACKED
                    ? wp8[(W2P_OFF >> 3) + (ks * 16 + tile) * 64 + lane]
                    : bfrag(w2, HID, ks * 32 + lq * 8, tile * 16 + lr, 1 << 30);
                #pragma unroll
                for (int mt = 0; mt < 4; ++mt)
                    acc[mt][nt] = __builtin_amdgcn_mfma_f32_16x16x32_f16(a[mt], b, acc[mt][nt], 0, 0, 0);
            }
        }
        __syncthreads();
        #pragma unroll
        for (int nt = 0; nt < 4; ++nt) {
            const int n = (wv * 4 + nt) * 16 + lr;
            const float bb = b2[n];
            #pragma unroll
            for (int mt = 0; mt < 4; ++mt)
                #pragma unroll
                for (int r = 0; r < 4; ++r)
                    hbuf[(mt * 16 + lq * 4 + r) * H_S + n] = (_Float16)fmaxf(acc[mt][nt][r] + bb, 0.0f);
        }
    }
    __syncthreads();

    // ======== sigma partials (fp32) ========
    {
        const int s  = tid & 63;
        const int k0 = (tid >> 6) << 6;
        float a = 0.0f;
        #pragma unroll
        for (int i = 0; i < 8; ++i) {
            const half8 h = *reinterpret_cast<const half8*>(&hbuf[s * H_S + k0 + i * 8]);
            #pragma unroll
            for (int j = 0; j < 8; ++j) a += (float)h[j] * w_sig[k0 + i * 8 + j];
        }
        sigp[tid] = a;
    }

    // ======== dir layer (MFMA) ========
    float4v accd[4][2];
    float   db[2];
    {
        #pragma unroll
        for (int mt = 0; mt < 4; ++mt)
            #pragma unroll
            for (int nt = 0; nt < 2; ++nt) accd[mt][nt] = float4v{0.f, 0.f, 0.f, 0.f};

        for (int ks = 0; ks < 8; ++ks) {
            half8 a[4];
            #pragma unroll
            for (int mt = 0; mt < 4; ++mt)
                a[mt] = *reinterpret_cast<const half8*>(&hbuf[(mt * 16 + lr) * H_S + ks * 32 + lq * 8]);
            #pragma unroll
            for (int nt = 0; nt < 2; ++nt) {
                const int tile = wv * 2 + nt;
                const half8 b = PACKED
                    ? wp8[(WDP_OFF >> 3) + (ks * 8 + tile) * 64 + lane]
                    : bfrag(w_dir, HID_DIR, ks * 32 + lq * 8, tile * 16 + lr, 1 << 30);
                #pragma unroll
                for (int mt = 0; mt < 4; ++mt)
                    accd[mt][nt] = __builtin_amdgcn_mfma_f32_16x16x32_f16(a[mt], b, accd[mt][nt], 0, 0, 0);
            }
        }
        #pragma unroll
        for (int nt = 0; nt < 2; ++nt) {
            const int n = (wv * 2 + nt) * 16 + lr;
            float d = b_dir[n];
            for (int t = 0; t < D_DIR; ++t)
                d += encdir[t] * w_dir[(HID + t) * HID_DIR + n];
            db[nt] = d;
        }
    }
    __syncthreads();

    if (tid < NS) {
        sigb[tid] = sigp[tid] + sigp[tid + 64] + sigp[tid + 128] + sigp[tid + 192] + b_sig[0];
    }
    #pragma unroll
    for (int nt = 0; nt < 2; ++nt) {
        const int n = (wv * 2 + nt) * 16 + lr;
        #pragma unroll
        for (int mt = 0; mt < 4; ++mt)
            #pragma unroll
            for (int r = 0; r < 4; ++r)
                hbuf[(mt * 16 + lq * 4 + r) * HD_S + n] = (_Float16)fmaxf(accd[mt][nt][r] + db[nt], 0.0f);
    }
    __syncthreads();

    // ======== rgb head (fp32) ========
    {
        const int s = tid & 63;
        const int c = tid >> 6;
        if (c < 3) {
            float a = 0.0f;
            #pragma unroll
            for (int i = 0; i < 16; ++i) {
                const half8 h = *reinterpret_cast<const half8*>(&hbuf[s * HD_S + i * 8]);
                #pragma unroll
                for (int j = 0; j < 8; ++j) a += (float)h[j] * w_rgb[(i * 8 + j) * 3 + c];
            }
            a += b_rgb[c];
            rgbb[s * 3 + c] = 1.0f / (1.0f + expf(-a));
        }
    }
    __syncthreads();

    // ======== conditional f64 razor for sigma[63] ========
    if (fabsf(sigb[63]) < 0.02f) {
        {
            const double z63 = zd[63];
            const double p0 = (double)ro0 + (double)rd0 * z63;
            const double p1 = (double)ro1 + (double)rd1 * z63;
            const double p2 = (double)ro2 + (double)rd2 * z63;
            if (tid < D_PTS) {
                const int f = tid;
                double v;
                if (f < 3) {
                    v = (f == 0) ? p0 : ((f == 1) ? p1 : p2);
                } else {
                    const int ff = f - 3;
                    const int l = ff / 6;
                    const int r = ff - 6 * l;
                    const int c = r % 3;
                    const double x = ((c == 0) ? p0 : ((c == 1) ? p1 : p2)) * (double)(1 << l);
                    v = (r < 3) ? sin(x) : cos(x);
                }
                encD[f] = v;
            }
        }
        __syncthreads();
        {
            double acc = 0.0;
            for (int k = 0; k < D_PTS; ++k)
                acc += encD[k] * (double)w1[k * HID + tid];
            acc += (double)b1[tid];
            h1d[tid] = fmax(acc, 0.0);
        }
        __syncthreads();
        {
            double acc = 0.0;
            for (int k = 0; k < HID; ++k)
                acc += h1d[k] * (double)w2[k * HID + tid];
            acc += (double)b2[tid];
            h2d[tid] = fmax(acc, 0.0);
        }
        __syncthreads();
        if (tid < 64) {
            double p = 0.0;
            #pragma unroll
            for (int m = 0; m < 4; ++m)
                p += h2d[tid * 4 + m] * (double)w_sig[tid * 4 + m];
            #pragma unroll
            for (int off = 1; off < 64; off <<= 1)
                p += __shfl_xor(p, off, 64);
            if (tid == 0) sigb[63] = (float)(p + (double)b_sig[0]);
        }
    }
    __syncthreads();

    // ======== volume compositing (wave 0) ========
    if (tid < NS) {
        const int s = tid;
        const float sgv = sigb[s];
        const float zv  = zbuf[s];
        const float zn  = (s < 63) ? zbuf[s + 1] : 0.0f;
        const float dist = (s < 63) ? (zn - zv) : 1.0e10f;
        const float alpha = 1.0f - expf(-fmaxf(sgv, 0.0f) * dist * nrm);
        float P = 1.0f - alpha;
        #pragma unroll
        for (int off = 1; off < 64; off <<= 1) {
            const float p = __shfl_up(P, off, 64);
            if (s >= off) P *= p;
        }
        float T = __shfl_up(P, 1, 64);
        if (s == 0) T = 1.0f;
        const float wgt = alpha * T;
        float r0 = wgt * rgbb[s * 3 + 0];
        float r1 = wgt * rgbb[s * 3 + 1];
        float r2 = wgt * rgbb[s * 3 + 2];
        #pragma unroll
        for (int off = 32; off > 0; off >>= 1) {
            r0 += __shfl_xor(r0, off, 64);
            r1 += __shfl_xor(r1, off, 64);
            r2 += __shfl_xor(r2, off, 64);
        }
        if (s == 0) {
            out[ray * 3 + 0] = r0;
            out[ray * 3 + 1] = r1;
            out[ray * 3 + 2] = r2;
        }
    }
}

} // namespace

extern "C" void kernel_launch(void* const* d_in, const int* in_sizes, int n_in,
                              void* d_out, int out_size, void* d_ws, size_t ws_size,
                              hipStream_t stream) {
    const float* c2w    = (const float*)d_in[0];
    const float* t_rand = (const float*)d_in[1];
    const float* w1     = (const float*)d_in[2];
    const float* b1     = (const float*)d_in[3];
    const float* w2     = (const float*)d_in[4];
    const float* b2     = (const float*)d_in[5];
    const float* w_sig  = (const float*)d_in[6];
    const float* b_sig  = (const float*)d_in[7];
    const float* w_dir  = (const float*)d_in[8];
    const float* b_dir  = (const float*)d_in[9];
    const float* w_rgb  = (const float*)d_in[10];
    const float* b_rgb  = (const float*)d_in[11];

    (void)in_sizes; (void)n_in; (void)out_size;

    const bool packed = (ws_size >= (size_t)(WPACK_HALFS * 2));
    if (packed) {
        _Float16* wp = (_Float16*)d_ws;
        hipLaunchKernelGGL(prepack, dim3((WPACK_HALFS + NTH - 1) / NTH), dim3(NTH), 0, stream,
                           w1, w2, w_dir, wp);
        hipLaunchKernelGGL((nerf_fused<true>), dim3(100 * 100), dim3(NTH), 0, stream,
                           c2w, t_rand, w1, b1, w2, b2, w_sig, b_sig,
                           w_dir, b_dir, w_rgb, b_rgb, (const _Float16*)wp, (float*)d_out);
    } else {
        hipLaunchKernelGGL((nerf_fused<false>), dim3(100 * 100), dim3(NTH), 0, stream,
                           c2w, t_rand, w1, b1, w2, b2, w_sig, b_sig,
                           w_dir, b_dir, w_rgb, b_rgb, (const _Float16*)nullptr, (float*)d_out);
    }
}

// Round 14
// 310.325 us; speedup vs baseline: 12.1453x; 1.2266x over previous
//
#include <hip/hip_runtime.h>
#include <cstdint>
#include <cmath>

#define NTH 256

namespace {

typedef _Float16 half8 __attribute__((ext_vector_type(8)));
typedef float    float4v __attribute__((ext_vector_type(4)));

constexpr int IMG_W   = 100;
constexpr int NS      = 64;
constexpr int D_PTS   = 63;
constexpr int D_DIR   = 27;
constexpr int HID     = 256;
constexpr int HID_DIR = 128;
constexpr int KDIR    = 288;   // 256 H2 + 27 encdir + 5 pad

constexpr int ENC_H = 72;    // enc stride (halfs)
constexpr int H_S   = 296;   // hbuf stride (halfs): >=288, 16B-aligned rows
constexpr int HD_S  = 136;   // hd stride (halfs)

// Packed fragments: [ks][tile][lane][8] halfs; one dwordx4/lane per B-frag.
//   w1p:  ks=2, 16 tiles               -> 16384 halfs @ 0
//   w2p:  ks=8, 16 tiles               -> 65536 halfs @ 16384
//   wdp:  ks=9, 9 tiles (8 dir + sigma)-> 41472 halfs @ 81920
//   wrgb: ks=4, 1 tile                 ->  2048 halfs @ 123392
constexpr int W1P_OFF  = 0;
constexpr int W2P_OFF  = 16384;
constexpr int WDP_OFF  = 81920;
constexpr int WRGB_OFF = 123392;
constexpr int WPACK_HALFS = 125440;     // 250880 bytes

__global__ __launch_bounds__(NTH)
void prepack(const float* __restrict__ w1, const float* __restrict__ w2,
             const float* __restrict__ wd, const float* __restrict__ wsig,
             const float* __restrict__ wrgb, _Float16* __restrict__ wp)
{
    const int idx = blockIdx.x * NTH + threadIdx.x;
    if (idx >= WPACK_HALFS) return;
    const int j    = idx & 7;
    const int lane = (idx >> 3) & 63;
    const int kloc = (lane >> 4) * 8 + j;
    const int lr   = lane & 15;
    float v = 0.0f;
    if (idx < W2P_OFF) {                               // w1 (K pad 63->64)
        const int nt = (idx >> 9) & 15, ks = idx >> 13;
        const int k = ks * 32 + kloc;
        if (k < D_PTS) v = w1[k * HID + nt * 16 + lr];
    } else if (idx < WDP_OFF) {                        // w2
        const int t = idx - W2P_OFF;
        const int nt = (t >> 9) & 15, ks = t >> 13;
        v = w2[(ks * 32 + kloc) * HID + nt * 16 + lr];
    } else if (idx < WRGB_OFF) {                       // w_dir (+tail) & sigma col
        const int t = idx - WDP_OFF;
        const int q = t >> 9;
        const int ks = q / 9, tile = q - 9 * ks;
        const int k = ks * 32 + kloc;
        if (tile < 8) {
            if (k < HID + D_DIR) v = wd[k * HID_DIR + tile * 16 + lr];
        } else {
            if (lr == 0 && k < HID) v = wsig[k];
        }
    } else {                                           // w_rgb (N=3 in 16-tile)
        const int t = idx - WRGB_OFF;
        const int ks = t >> 9;
        const int k = ks * 32 + kloc;                  // k <= 127 always
        if (lr < 3) v = wrgb[k * 3 + lr];
    }
    wp[idx] = (_Float16)v;
}

// Fallback gathers (no workspace): 8 scalar fp32 loads + cvt.
__device__ __forceinline__ half8 bf_w(const float* __restrict__ W, int ldN,
                                      int kbase, int n, int kmax) {
    half8 b;
    #pragma unroll
    for (int j = 0; j < 8; ++j) {
        const int k = kbase + j;
        b[j] = (_Float16)((k < kmax) ? W[k * ldN + n] : 0.0f);
    }
    return b;
}
__device__ __forceinline__ half8 bf_sig(const float* __restrict__ ws, int kbase, int lr) {
    half8 b;
    #pragma unroll
    for (int j = 0; j < 8; ++j) {
        const int k = kbase + j;
        b[j] = (_Float16)((lr == 0 && k < HID) ? ws[k] : 0.0f);
    }
    return b;
}
__device__ __forceinline__ half8 bf_rgb(const float* __restrict__ wr, int kbase, int lr) {
    half8 b;
    #pragma unroll
    for (int j = 0; j < 8; ++j) {
        const int k = kbase + j;
        b[j] = (_Float16)((lr < 3) ? wr[k * 3 + lr] : 0.0f);
    }
    return b;
}

template<bool PACKED>
__global__ __launch_bounds__(NTH, 3)
void nerf_fused(const float* __restrict__ c2w,
                const float* __restrict__ t_rand,
                const float* __restrict__ w1,  const float* __restrict__ b1,
                const float* __restrict__ w2,  const float* __restrict__ b2,
                const float* __restrict__ w_sig, const float* __restrict__ b_sig,
                const float* __restrict__ w_dir, const float* __restrict__ b_dir,
                const float* __restrict__ w_rgb, const float* __restrict__ b_rgb,
                const _Float16* __restrict__ wpack,
                float* __restrict__ out)
{
    __shared__ __align__(16) unsigned char scrA[NS * ENC_H * 2];       // 9216 B
    _Float16* encH = reinterpret_cast<_Float16*>(scrA);
    double*   encD = reinterpret_cast<double*>(scrA);                  //  512 B
    double*   h1d  = reinterpret_cast<double*>(scrA + 512);            // 2048 B
    double*   h2d  = reinterpret_cast<double*>(scrA + 2560);           // 2048 B
    __shared__ __align__(16) _Float16 hbuf[NS * H_S];                  // 37888 B
    __shared__ float  zbuf[NS];
    __shared__ double zd[NS];
    __shared__ float  encdir[32];
    __shared__ float  sigb[NS];
    __shared__ float  rgbb[NS * 3];

    const int tid  = threadIdx.x;
    const int ray  = blockIdx.x;
    const int lane = tid & 63;
    const int wv   = tid >> 6;
    const int lr   = lane & 15;
    const int lq   = lane >> 4;

    const half8* wp8 = reinterpret_cast<const half8*>(wpack);

    // ---- per-ray setup ----
    const int pj = ray / IMG_W;
    const int pi = ray - pj * IMG_W;
    const float dx = ((float)pi - 50.0f) / 86.6f;
    const float dy = -(((float)pj) - 50.0f) / 86.6f;
    const float rd0 = dx * c2w[0] + dy * c2w[1] - c2w[2];
    const float rd1 = dx * c2w[4] + dy * c2w[5] - c2w[6];
    const float rd2 = dx * c2w[8] + dy * c2w[9] - c2w[10];
    const float ro0 = c2w[3], ro1 = c2w[7], ro2 = c2w[11];
    const float nrm = sqrtf(rd0 * rd0 + rd1 * rd1 + rd2 * rd2);
    const float vd0 = rd0 / nrm, vd1 = rd1 / nrm, vd2 = rd2 / nrm;

    // ---- z: np.linspace-style f64 chain (t[63]=1 exact) ----
    if (tid < NS) {
        const int s = tid;
        const double delta = 1.0 / 63.0;
        const double ts = (s == 63) ? 1.0 : (double)s * delta;
        const double zs = 2.0 * (1.0 - ts) + 6.0 * ts;
        double lower, upper;
        if (s == 0) { lower = zs; }
        else { const double tm = (double)(s - 1) * delta;
               const double zm = 2.0 * (1.0 - tm) + 6.0 * tm; lower = 0.5 * (zm + zs); }
        if (s == 63) { upper = zs; }
        else { const double tp = (s + 1 == 63) ? 1.0 : (double)(s + 1) * delta;
               const double zp = 2.0 * (1.0 - tp) + 6.0 * tp; upper = 0.5 * (zs + zp); }
        const double zz = lower + (upper - lower) * (double)t_rand[s];
        zd[s]   = zz;
        zbuf[s] = (float)zz;
    }
    if (tid < 32) {
        float v = 0.0f;
        if (tid < D_DIR) {
            const int f = tid;
            if (f < 3) {
                v = (f == 0) ? vd0 : ((f == 1) ? vd1 : vd2);
            } else {
                const int ff = f - 3;
                const int l = ff / 6;
                const int r = ff - 6 * l;
                const int c = r % 3;
                const float x = ((c == 0) ? vd0 : ((c == 1) ? vd1 : vd2)) * (float)(1 << l);
                v = (r < 3) ? sinf(x) : cosf(x);
            }
        }
        encdir[tid] = v;
    }
    __syncthreads();

    // ---- enc_pts via double-angle recurrence (192 threads: one (s,coord)) ----
    if (tid < 192) {
        const int s = tid / 3;
        const int c = tid - 3 * s;
        const float zv = zbuf[s];
        const float p = (c == 0) ? (ro0 + rd0 * zv) : ((c == 1) ? (ro1 + rd1 * zv) : (ro2 + rd2 * zv));
        _Float16* row = &encH[s * ENC_H];
        row[c] = (_Float16)p;
        float sl = sinf(p), cl = cosf(p);
        row[3 + c] = (_Float16)sl;
        row[6 + c] = (_Float16)cl;
        #pragma unroll
        for (int l = 1; l < 10; ++l) {
            const float s2 = 2.0f * sl * cl;
            const float c2 = 1.0f - 2.0f * sl * sl;
            row[3 + 6 * l + c]     = (_Float16)s2;
            row[3 + 6 * l + 3 + c] = (_Float16)c2;
            sl = s2; cl = c2;
        }
    }
    if (tid < 64) encH[tid * ENC_H + 63] = (_Float16)0.0f;   // K-pad col
    // encdir -> hbuf K-extension cols 256..287 (dir-layer tail via MFMA)
    {
        const int s  = tid >> 2;
        const int t0 = (tid & 3) * 8;
        half8 v;
        #pragma unroll
        for (int j = 0; j < 8; ++j) v[j] = (_Float16)encdir[t0 + j];
        *reinterpret_cast<half8*>(&hbuf[s * H_S + 256 + t0]) = v;
    }
    __syncthreads();

    // ======== layer 1 (MFMA): H1 = relu(enc @ w1 + b1) ========
    {
        float4v acc[4][4];
        #pragma unroll
        for (int mt = 0; mt < 4; ++mt)
            #pragma unroll
            for (int nt = 0; nt < 4; ++nt) acc[mt][nt] = float4v{0.f, 0.f, 0.f, 0.f};

        #pragma unroll
        for (int ks = 0; ks < 2; ++ks) {
            half8 a[4];
            #pragma unroll
            for (int mt = 0; mt < 4; ++mt)
                a[mt] = *reinterpret_cast<const half8*>(&encH[(mt * 16 + lr) * ENC_H + ks * 32 + lq * 8]);
            #pragma unroll
            for (int nt = 0; nt < 4; ++nt) {
                const int tile = wv * 4 + nt;
                const half8 b = PACKED
                    ? wp8[(W1P_OFF >> 3) + (ks * 16 + tile) * 64 + lane]
                    : bf_w(w1, HID, ks * 32 + lq * 8, tile * 16 + lr, D_PTS);
                #pragma unroll
                for (int mt = 0; mt < 4; ++mt)
                    acc[mt][nt] = __builtin_amdgcn_mfma_f32_16x16x32_f16(a[mt], b, acc[mt][nt], 0, 0, 0);
            }
        }
        #pragma unroll
        for (int nt = 0; nt < 4; ++nt) {
            const int n = (wv * 4 + nt) * 16 + lr;
            const float bb = b1[n];
            #pragma unroll
            for (int mt = 0; mt < 4; ++mt)
                #pragma unroll
                for (int r = 0; r < 4; ++r)
                    hbuf[(mt * 16 + lq * 4 + r) * H_S + n] = (_Float16)fmaxf(acc[mt][nt][r] + bb, 0.0f);
        }
    }
    __syncthreads();

    // ======== layer 2 (MFMA): H2 = relu(H1 @ w2 + b2) ========
    {
        float4v acc[4][4];
        #pragma unroll
        for (int mt = 0; mt < 4; ++mt)
            #pragma unroll
            for (int nt = 0; nt < 4; ++nt) acc[mt][nt] = float4v{0.f, 0.f, 0.f, 0.f};

        for (int ks = 0; ks < 8; ++ks) {
            half8 a[4];
            #pragma unroll
            for (int mt = 0; mt < 4; ++mt)
                a[mt] = *reinterpret_cast<const half8*>(&hbuf[(mt * 16 + lr) * H_S + ks * 32 + lq * 8]);
            #pragma unroll
            for (int nt = 0; nt < 4; ++nt) {
                const int tile = wv * 4 + nt;
                const half8 b = PACKED
                    ? wp8[(W2P_OFF >> 3) + (ks * 16 + tile) * 64 + lane]
                    : bf_w(w2, HID, ks * 32 + lq * 8, tile * 16 + lr, 1 << 30);
                #pragma unroll
                for (int mt = 0; mt < 4; ++mt)
                    acc[mt][nt] = __builtin_amdgcn_mfma_f32_16x16x32_f16(a[mt], b, acc[mt][nt], 0, 0, 0);
            }
        }
        __syncthreads();   // all H1 reads complete before in-place overwrite
        #pragma unroll
        for (int nt = 0; nt < 4; ++nt) {
            const int n = (wv * 4 + nt) * 16 + lr;
            const float bb = b2[n];
            #pragma unroll
            for (int mt = 0; mt < 4; ++mt)
                #pragma unroll
                for (int r = 0; r < 4; ++r)
                    hbuf[(mt * 16 + lq * 4 + r) * H_S + n] = (_Float16)fmaxf(acc[mt][nt][r] + bb, 0.0f);
        }
    }
    __syncthreads();

    // ======== dir layer + sigma (MFMA, K=288 incl. encdir tail) ========
    float4v accd[4][2];
    float4v accs[4];   // sigma tile (wave 0 only)
    {
        #pragma unroll
        for (int mt = 0; mt < 4; ++mt) {
            #pragma unroll
            for (int nt = 0; nt < 2; ++nt) accd[mt][nt] = float4v{0.f, 0.f, 0.f, 0.f};
            accs[mt] = float4v{0.f, 0.f, 0.f, 0.f};
        }
        for (int ks = 0; ks < 9; ++ks) {
            half8 a[4];
            #pragma unroll
            for (int mt = 0; mt < 4; ++mt)
                a[mt] = *reinterpret_cast<const half8*>(&hbuf[(mt * 16 + lr) * H_S + ks * 32 + lq * 8]);
            #pragma unroll
            for (int nt = 0; nt < 2; ++nt) {
                const int tile = wv * 2 + nt;
                const half8 b = PACKED
                    ? wp8[(WDP_OFF >> 3) + (ks * 9 + tile) * 64 + lane]
                    : bf_w(w_dir, HID_DIR, ks * 32 + lq * 8, tile * 16 + lr, HID + D_DIR);
                #pragma unroll
                for (int mt = 0; mt < 4; ++mt)
                    accd[mt][nt] = __builtin_amdgcn_mfma_f32_16x16x32_f16(a[mt], b, accd[mt][nt], 0, 0, 0);
            }
            if (wv == 0) {
                const half8 b = PACKED
                    ? wp8[(WDP_OFF >> 3) + (ks * 9 + 8) * 64 + lane]
                    : bf_sig(w_sig, ks * 32 + lq * 8, lr);
                #pragma unroll
                for (int mt = 0; mt < 4; ++mt)
                    accs[mt] = __builtin_amdgcn_mfma_f32_16x16x32_f16(a[mt], b, accs[mt], 0, 0, 0);
            }
        }
    }
    __syncthreads();   // all H2/encdir reads complete

    // HD -> hbuf (HD_S layout); sigma -> sigb
    #pragma unroll
    for (int nt = 0; nt < 2; ++nt) {
        const int n = (wv * 2 + nt) * 16 + lr;
        const float bb = b_dir[n];
        #pragma unroll
        for (int mt = 0; mt < 4; ++mt)
            #pragma unroll
            for (int r = 0; r < 4; ++r)
                hbuf[(mt * 16 + lq * 4 + r) * HD_S + n] = (_Float16)fmaxf(accd[mt][nt][r] + bb, 0.0f);
    }
    if (wv == 0 && lr == 0) {
        const float bs = b_sig[0];
        #pragma unroll
        for (int mt = 0; mt < 4; ++mt)
            #pragma unroll
            for (int r = 0; r < 4; ++r)
                sigb[mt * 16 + lq * 4 + r] = accs[mt][r] + bs;
    }
    __syncthreads();

    // ======== rgb head (MFMA): each wave does m-tile wv ========
    {
        float4v accr = float4v{0.f, 0.f, 0.f, 0.f};
        #pragma unroll
        for (int ks = 0; ks < 4; ++ks) {
            const half8 a = *reinterpret_cast<const half8*>(&hbuf[(wv * 16 + lr) * HD_S + ks * 32 + lq * 8]);
            const half8 b = PACKED
                ? wp8[(WRGB_OFF >> 3) + ks * 64 + lane]
                : bf_rgb(w_rgb, ks * 32 + lq * 8, lr);
            accr = __builtin_amdgcn_mfma_f32_16x16x32_f16(a, b, accr, 0, 0, 0);
        }
        if (lr < 3) {
            const float bb = b_rgb[lr];
            #pragma unroll
            for (int r = 0; r < 4; ++r) {
                const float a = accr[r] + bb;
                rgbb[(wv * 16 + lq * 4 + r) * 3 + lr] = 1.0f / (1.0f + expf(-a));
            }
        }
    }
    __syncthreads();

    // ======== conditional f64 razor for sigma[63] (aliases dead encH) ========
    if (fabsf(sigb[63]) < 0.02f) {
        {
            const double z63 = zd[63];
            const double p0 = (double)ro0 + (double)rd0 * z63;
            const double p1 = (double)ro1 + (double)rd1 * z63;
            const double p2 = (double)ro2 + (double)rd2 * z63;
            if (tid < D_PTS) {
                const int f = tid;
                double v;
                if (f < 3) {
                    v = (f == 0) ? p0 : ((f == 1) ? p1 : p2);
                } else {
                    const int ff = f - 3;
                    const int l = ff / 6;
                    const int r = ff - 6 * l;
                    const int c = r % 3;
                    const double x = ((c == 0) ? p0 : ((c == 1) ? p1 : p2)) * (double)(1 << l);
                    v = (r < 3) ? sin(x) : cos(x);
                }
                encD[f] = v;
            }
        }
        __syncthreads();
        {
            double acc = 0.0;
            for (int k = 0; k < D_PTS; ++k)
                acc += encD[k] * (double)w1[k * HID + tid];
            acc += (double)b1[tid];
            h1d[tid] = fmax(acc, 0.0);
        }
        __syncthreads();
        {
            double acc = 0.0;
            for (int k = 0; k < HID; ++k)
                acc += h1d[k] * (double)w2[k * HID + tid];
            acc += (double)b2[tid];
            h2d[tid] = fmax(acc, 0.0);
        }
        __syncthreads();
        if (tid < 64) {
            double p = 0.0;
            #pragma unroll
            for (int m = 0; m < 4; ++m)
                p += h2d[tid * 4 + m] * (double)w_sig[tid * 4 + m];
            #pragma unroll
            for (int off = 1; off < 64; off <<= 1)
                p += __shfl_xor(p, off, 64);
            if (tid == 0) sigb[63] = (float)(p + (double)b_sig[0]);
        }
    }
    __syncthreads();

    // ======== volume compositing (wave 0) ========
    if (tid < NS) {
        const int s = tid;
        const float sgv = sigb[s];
        const float zv  = zbuf[s];
        const float zn  = (s < 63) ? zbuf[s + 1] : 0.0f;
        const float dist = (s < 63) ? (zn - zv) : 1.0e10f;
        const float alpha = 1.0f - expf(-fmaxf(sgv, 0.0f) * dist * nrm);
        float P = 1.0f - alpha;
        #pragma unroll
        for (int off = 1; off < 64; off <<= 1) {
            const float p = __shfl_up(P, off, 64);
            if (s >= off) P *= p;
        }
        float T = __shfl_up(P, 1, 64);
        if (s == 0) T = 1.0f;
        const float wgt = alpha * T;
        float r0 = wgt * rgbb[s * 3 + 0];
        float r1 = wgt * rgbb[s * 3 + 1];
        float r2 = wgt * rgbb[s * 3 + 2];
        #pragma unroll
        for (int off = 32; off > 0; off >>= 1) {
            r0 += __shfl_xor(r0, off, 64);
            r1 += __shfl_xor(r1, off, 64);
            r2 += __shfl_xor(r2, off, 64);
        }
        if (s == 0) {
            out[ray * 3 + 0] = r0;
            out[ray * 3 + 1] = r1;
            out[ray * 3 + 2] = r2;
        }
    }
}

} // namespace

extern "C" void kernel_launch(void* const* d_in, const int* in_sizes, int n_in,
                              void* d_out, int out_size, void* d_ws, size_t ws_size,
                              hipStream_t stream) {
    const float* c2w    = (const float*)d_in[0];
    const float* t_rand = (const float*)d_in[1];
    const float* w1     = (const float*)d_in[2];
    const float* b1     = (const float*)d_in[3];
    const float* w2     = (const float*)d_in[4];
    const float* b2     = (const float*)d_in[5];
    const float* w_sig  = (const float*)d_in[6];
    const float* b_sig  = (const float*)d_in[7];
    const float* w_dir  = (const float*)d_in[8];
    const float* b_dir  = (const float*)d_in[9];
    const float* w_rgb  = (const float*)d_in[10];
    const float* b_rgb  = (const float*)d_in[11];

    (void)in_sizes; (void)n_in; (void)out_size;

    const bool packed = (ws_size >= (size_t)(WPACK_HALFS * 2));
    if (packed) {
        _Float16* wp = (_Float16*)d_ws;
        hipLaunchKernelGGL(prepack, dim3((WPACK_HALFS + NTH - 1) / NTH), dim3(NTH), 0, stream,
                           w1, w2, w_dir, w_sig, w_rgb, wp);
        hipLaunchKernelGGL((nerf_fused<true>), dim3(100 * 100), dim3(NTH), 0, stream,
                           c2w, t_rand, w1, b1, w2, b2, w_sig, b_sig,
                           w_dir, b_dir, w_rgb, b_rgb, (const _Float16*)wp, (float*)d_out);
    } else {
        hipLaunchKernelGGL((nerf_fused<false>), dim3(100 * 100), dim3(NTH), 0, stream,
                           c2w, t_rand, w1, b1, w2, b2, w_sig, b_sig,
                           w_dir, b_dir, w_rgb, b_rgb, (const _Float16*)nullptr, (float*)d_out);
    }
}